// Round 9
// baseline (291.686 us; speedup 1.0000x reference)
//
#include <hip/hip_runtime.h>
#include <hip/hip_bf16.h>
#include <hip/hip_fp16.h>

#define NN 100000
#define NE 3200000
#define IN_F 128
#define HID 32

#define NB 782          // buckets: bucket = dst >> 7, 128 nodes each
#define NBP1 (NB + 1)
#define BNODES 128
#define PBLK 392        // partition blocks
#define EPB 8192        // edges per partition block (512 thr x 16)
#define SSPAN 4608      // sorted span per bucket (mean 4096 + 8 sigma)

typedef __hip_bfloat16 bf16;
typedef __attribute__((ext_vector_type(8))) short s16x8;   // 8 bf16 (4 VGPRs)
typedef __attribute__((ext_vector_type(4))) float f32x4;   // MFMA C/D

// ---------------- partition: 2-pass, direct scatter into block-private window ----------------
__global__ __launch_bounds__(512) void k_part(const int* __restrict__ ei,
                                              const float* __restrict__ ew,
                                              int* __restrict__ offs,
                                              uint2* __restrict__ raw) {
    __shared__ int hist[NB];
    __shared__ int start[NB];
    __shared__ int wtot8[8];

    int t = threadIdx.x;
    int blk = blockIdx.x;
    for (int b = t; b < NB; b += 512) hist[b] = 0;
    __syncthreads();

    int base_e = blk * EPB;
    // pass A: histogram destinations
#pragma unroll
    for (int j = 0; j < 16; j++) {
        int e = base_e + j * 512 + t;
        if (e < NE) {
            int dst = __builtin_nontemporal_load(ei + NE + e);
            atomicAdd(&hist[dst >> 7], 1);
        }
    }
    __syncthreads();

    // exclusive scan over 782 bins (512 threads x 2, shuffle-based)
    int e0 = 2 * t, e1 = 2 * t + 1;
    int h0 = (e0 < NB) ? hist[e0] : 0;
    int h1 = (e1 < NB) ? hist[e1] : 0;
    int psum = h0 + h1;
    int lane = t & 63;
    int incl = psum;
#pragma unroll
    for (int off = 1; off < 64; off <<= 1) {
        int up = __shfl_up(incl, off, 64);
        if (lane >= off) incl += up;
    }
    int wid = t >> 6;
    if (lane == 63) wtot8[wid] = incl;
    __syncthreads();
    int woff = 0;
    for (int wj = 0; wj < wid; wj++) woff += wtot8[wj];
    int exc = woff + incl - psum;
    if (e0 < NB) start[e0] = exc;
    if (e1 < NB) start[e1] = exc + h0;
    __syncthreads();

    int total = start[NB - 1] + hist[NB - 1];
    int* orow = offs + (size_t)blk * NBP1;
    for (int b = t; b < NB; b += 512) orow[b] = start[b];
    if (t == 0) orow[NB] = total;
    __syncthreads();   // orow must be written before start[] becomes cursors

    // pass B: re-read edges, scatter 8B records into private 64KB window
#pragma unroll
    for (int j = 0; j < 16; j++) {
        int e = base_e + j * 512 + t;
        if (e < NE) {
            int src = __builtin_nontemporal_load(ei + e);
            int dst = __builtin_nontemporal_load(ei + NE + e);
            float w = __builtin_nontemporal_load(ew + e);
            int bkt = dst >> 7;
            unsigned pk = (unsigned)src | ((unsigned)(dst & 127) << 20);
            int pos = atomicAdd(&start[bkt], 1);
            raw[(size_t)blk * EPB + pos] = make_uint2(pk, __float_as_uint(w));
        }
    }
}

// ---------------- offs transpose (row-major [blk][bucket] -> [bucket][blk]) ----------------
__global__ __launch_bounds__(256) void k_trans(const int* __restrict__ in, int* __restrict__ out) {
    __shared__ int tile[32][33];
    int c0 = blockIdx.x * 32, r0 = blockIdx.y * 32;
    int tx = threadIdx.x & 31, ty = threadIdx.x >> 5;   // 32 x 8
    for (int i = ty; i < 32; i += 8) {
        int r = r0 + i, c = c0 + tx;
        if (r < PBLK && c < NBP1) tile[i][tx] = in[(size_t)r * NBP1 + c];
    }
    __syncthreads();
    for (int i = ty; i < 32; i += 8) {
        int c = c0 + i, r = r0 + tx;
        if (c < NBP1 && r < PBLK) out[(size_t)c * PBLK + r] = tile[tx][i];
    }
}

// ---------------- per-bucket parallel gather + counting sort + CSR meta ----------------
__global__ __launch_bounds__(256) void k_sort(const int* __restrict__ offsT,
                                              const uint2* __restrict__ raw,
                                              unsigned* __restrict__ srt1,
                                              unsigned short* __restrict__ srt2,
                                              int* __restrict__ rowstart,
                                              int* __restrict__ rowcnt,
                                              float* __restrict__ dinv) {
    __shared__ uint2 se[SSPAN];               // 36.9 KB
    __shared__ unsigned short runid[SSPAN];   //  9.2 KB
    __shared__ int P[PBLK + 1];
    __shared__ int O0[PBLK];
    __shared__ int hist[BNODES];
    __shared__ float wsum[BNODES];
    __shared__ int scanbuf[BNODES];
    __shared__ int cur[BNODES];
    __shared__ int wt4[4];

    int t = threadIdx.x;
    int b = blockIdx.x;
    if (t < BNODES) { hist[t] = 0; wsum[t] = 1.0f; }  // self-loop weight 1

    // run lengths for this bucket across all 392 partition blocks (coalesced rows)
    int e0 = 2 * t, e1 = 2 * t + 1;
    int l0 = 0, l1 = 0;
    if (e0 < PBLK) {
        int o0 = offsT[(size_t)b * PBLK + e0];
        l0 = offsT[(size_t)(b + 1) * PBLK + e0] - o0;
        O0[e0] = o0;
    }
    if (e1 < PBLK) {
        int o1 = offsT[(size_t)b * PBLK + e1];
        l1 = offsT[(size_t)(b + 1) * PBLK + e1] - o1;
        O0[e1] = o1;
    }
    int psum = l0 + l1;
    int lane = t & 63;
    int incl = psum;
#pragma unroll
    for (int off = 1; off < 64; off <<= 1) {
        int up = __shfl_up(incl, off, 64);
        if (lane >= off) incl += up;
    }
    int wid = t >> 6;
    if (lane == 63) wt4[wid] = incl;
    __syncthreads();
    int woff = 0;
    for (int wj = 0; wj < wid; wj++) woff += wt4[wj];
    int exc = woff + incl - psum;
    if (e0 < PBLK) P[e0] = exc;
    if (e1 < PBLK) P[e1] = exc + l0;
    if (t == 0) P[PBLK] = wt4[0] + wt4[1] + wt4[2] + wt4[3];
    __syncthreads();

    int total = min(P[PBLK], SSPAN);

    // build d -> run map (short serial LDS fills, ~10 per run)
    for (int r = t; r < PBLK; r += 256) {
        int p0 = P[r], p1 = min(P[r + 1], SSPAN);
        for (int i = p0; i < p1; i++) runid[i] = (unsigned short)r;
    }
    __syncthreads();

    // parallel coalesced gather + node histogram
    for (int d = t; d < total; d += 256) {
        int r = runid[d];
        uint2 rec = raw[(size_t)r * EPB + O0[r] + (d - P[r])];
        se[d] = rec;
        int dl = (rec.x >> 20) & 127;
        atomicAdd(&hist[dl], 1);
        atomicAdd(&wsum[dl], __uint_as_float(rec.y));
    }
    __syncthreads();

    // inclusive scan of node hist (Hillis-Steele over 128)
    if (t < BNODES) scanbuf[t] = hist[t];
    __syncthreads();
    for (int off = 1; off < BNODES; off <<= 1) {
        int v = 0;
        if (t < BNODES && t >= off) v = scanbuf[t - off];
        __syncthreads();
        if (t < BNODES) scanbuf[t] += v;
        __syncthreads();
    }

    int obase = b * SSPAN;
    if (t < BNODES) {
        int binstart = scanbuf[t] - hist[t];  // exclusive
        cur[t] = binstart;
        int node = b * BNODES + t;
        if (node < NN) {
            rowstart[node] = obase + binstart;
            rowcnt[node]   = hist[t];
            dinv[node]     = rsqrtf(wsum[t]);
        }
    }
    __syncthreads();

    // scatter sorted by node (dense within bucket span), weight -> fp16
    for (int i = t; i < total; i += 256) {
        uint2 rec = se[i];
        int dl = (rec.x >> 20) & 127;
        int pos = atomicAdd(&cur[dl], 1);     // LDS atomic
        srt1[obase + pos] = rec.x & 0xFFFFF;
        srt2[obase + pos] = __half_as_ushort(__float2half(__uint_as_float(rec.y)));
    }
}

// ---------------- W1 -> bf16 MFMA B-fragments, lane-packed ----------------
__global__ void k_w1frag(const float* __restrict__ W1, unsigned short* __restrict__ wfrag) {
    int lane = threadIdx.x;   // 64 threads
    int q = lane >> 4;
    int n0 = lane & 15;
#pragma unroll
    for (int ks = 0; ks < 4; ks++) {
#pragma unroll
        for (int nt = 0; nt < 2; nt++) {
            int fi = ks * 2 + nt;
            int n = n0 + 16 * nt;
#pragma unroll
            for (int j = 0; j < 8; j++) {
                int k = ks * 32 + q * 8 + j;
                float v = W1[k * HID + n];
                __hip_bfloat16 bv = __float2bfloat16(v);
                wfrag[((size_t)fi * 64 + lane) * 8 + j] = *(unsigned short*)&bv;
            }
        }
    }
}

// ---------------- hs = dinv * (x @ W1) via MFMA, stored bf16 ----------------
__global__ __launch_bounds__(256) void k_hs(const float* __restrict__ x,
                                            const unsigned short* __restrict__ wfrag,
                                            const float* __restrict__ dinv,
                                            bf16* __restrict__ hs) {
    int t = threadIdx.x;
    int lane = t & 63;
    int wv = t >> 6;
    int base = blockIdx.x * 64 + wv * 16;
    int m = lane & 15;
    int q = lane >> 4;
    int node = base + m;

    s16x8 wf[8];
    const s16x8* wp = (const s16x8*)wfrag;
#pragma unroll
    for (int fi = 0; fi < 8; fi++) wf[fi] = wp[fi * 64 + lane];

    f32x4 acc0 = {0.f, 0.f, 0.f, 0.f};
    f32x4 acc1 = {0.f, 0.f, 0.f, 0.f};

    const float* rowp = x + (size_t)node * IN_F + q * 8;
    bool valid = (node < NN);

#pragma unroll
    for (int ks = 0; ks < 4; ks++) {
        float4 f0 = {0,0,0,0}, f1 = {0,0,0,0};
        if (valid) {
            const float4* xr = (const float4*)(rowp + ks * 32);
            f0 = xr[0]; f1 = xr[1];
        }
        union { s16x8 v; unsigned u32[4]; } af;
        __hip_bfloat162 p0 = __float22bfloat162_rn({f0.x, f0.y});
        __hip_bfloat162 p1 = __float22bfloat162_rn({f0.z, f0.w});
        __hip_bfloat162 p2 = __float22bfloat162_rn({f1.x, f1.y});
        __hip_bfloat162 p3 = __float22bfloat162_rn({f1.z, f1.w});
        af.u32[0] = *(unsigned*)&p0;
        af.u32[1] = *(unsigned*)&p1;
        af.u32[2] = *(unsigned*)&p2;
        af.u32[3] = *(unsigned*)&p3;
        acc0 = __builtin_amdgcn_mfma_f32_16x16x32_bf16(af.v, wf[ks * 2 + 0], acc0, 0, 0, 0);
        acc1 = __builtin_amdgcn_mfma_f32_16x16x32_bf16(af.v, wf[ks * 2 + 1], acc1, 0, 0, 0);
    }

    int f = lane & 15;
#pragma unroll
    for (int r = 0; r < 4; r++) {
        int n2 = base + q * 4 + r;
        if (n2 < NN) {
            float dv = dinv[n2];
            hs[(size_t)n2 * HID + f]      = __float2bfloat16(dv * acc0[r]);
            hs[(size_t)n2 * HID + f + 16] = __float2bfloat16(dv * acc1[r]);
        }
    }
}

// ---------------- node-parallel pull aggregation + fused epilogue ----------------
// 16 lanes/node x 2 feats/lane (wave = 4 nodes)
__global__ __launch_bounds__(256) void k_agg(const int* __restrict__ rowstart,
                                             const int* __restrict__ rowcnt,
                                             const unsigned* __restrict__ srcs,
                                             const unsigned short* __restrict__ wts,
                                             const bf16* __restrict__ hs,
                                             const float* __restrict__ dinv,
                                             const float* __restrict__ b1, const float* __restrict__ W2,
                                             const float* __restrict__ b2, float* __restrict__ out) {
    int t = threadIdx.x;
    int l = t & 15;                          // lane within node group
    int node = blockIdx.x * 16 + (t >> 4);   // NN % 16 == 0
    int rs = rowstart[node];
    int re = rs + rowcnt[node];
    const __hip_bfloat162* hs2 = (const __hip_bfloat162*)hs;  // row stride 16
    float acc0 = 0.f, acc1 = 0.f;

    for (int base = rs; base < re; base += 16) {
        int idx = base + l;
        int sreg = 0; float wreg = 0.f;
        if (idx < re) {
            sreg = (int)srcs[idx];
            wreg = __half2float(__ushort_as_half(wts[idx]));
        }
        int m = min(16, re - base);
        int j = 0;
        for (; j + 8 <= m; j += 8) {
            int s0 = __shfl(sreg, j + 0, 16), s1 = __shfl(sreg, j + 1, 16);
            int s2 = __shfl(sreg, j + 2, 16), s3 = __shfl(sreg, j + 3, 16);
            int s4 = __shfl(sreg, j + 4, 16), s5 = __shfl(sreg, j + 5, 16);
            int s6 = __shfl(sreg, j + 6, 16), s7 = __shfl(sreg, j + 7, 16);
            float w0 = __shfl(wreg, j + 0, 16), w1 = __shfl(wreg, j + 1, 16);
            float w2 = __shfl(wreg, j + 2, 16), w3 = __shfl(wreg, j + 3, 16);
            float w4 = __shfl(wreg, j + 4, 16), w5 = __shfl(wreg, j + 5, 16);
            float w6 = __shfl(wreg, j + 6, 16), w7 = __shfl(wreg, j + 7, 16);
            __hip_bfloat162 h0 = hs2[(size_t)s0 * 16 + l];
            __hip_bfloat162 h1 = hs2[(size_t)s1 * 16 + l];
            __hip_bfloat162 h2 = hs2[(size_t)s2 * 16 + l];
            __hip_bfloat162 h3 = hs2[(size_t)s3 * 16 + l];
            __hip_bfloat162 h4 = hs2[(size_t)s4 * 16 + l];
            __hip_bfloat162 h5 = hs2[(size_t)s5 * 16 + l];
            __hip_bfloat162 h6 = hs2[(size_t)s6 * 16 + l];
            __hip_bfloat162 h7 = hs2[(size_t)s7 * 16 + l];
            float2 f0 = __bfloat1622float2(h0); acc0 += w0 * f0.x; acc1 += w0 * f0.y;
            float2 f1 = __bfloat1622float2(h1); acc0 += w1 * f1.x; acc1 += w1 * f1.y;
            float2 f2 = __bfloat1622float2(h2); acc0 += w2 * f2.x; acc1 += w2 * f2.y;
            float2 f3 = __bfloat1622float2(h3); acc0 += w3 * f3.x; acc1 += w3 * f3.y;
            float2 f4 = __bfloat1622float2(h4); acc0 += w4 * f4.x; acc1 += w4 * f4.y;
            float2 f5 = __bfloat1622float2(h5); acc0 += w5 * f5.x; acc1 += w5 * f5.y;
            float2 f6 = __bfloat1622float2(h6); acc0 += w6 * f6.x; acc1 += w6 * f6.y;
            float2 f7 = __bfloat1622float2(h7); acc0 += w7 * f7.x; acc1 += w7 * f7.y;
        }
        for (; j < m; j++) {
            int s = __shfl(sreg, j, 16);
            float w = __shfl(wreg, j, 16);
            float2 fv = __bfloat1622float2(hs2[(size_t)s * 16 + l]);
            acc0 += w * fv.x; acc1 += w * fv.y;
        }
    }

    float2 fs = __bfloat1622float2(hs2[(size_t)node * 16 + l]);
    float dv = dinv[node];
    float v0 = dv * (acc0 + fs.x) + b1[2 * l];
    float v1 = dv * (acc1 + fs.y) + b1[2 * l + 1];
    v0 = fmaxf(v0, 0.f);
    v1 = fmaxf(v1, 0.f);
    float psum = v0 * W2[2 * l] + v1 * W2[2 * l + 1];
#pragma unroll
    for (int m2 = 8; m2 >= 1; m2 >>= 1) psum += __shfl_xor(psum, m2, 16);
    if (l == 0) out[node] = psum + b2[0];
}

// ---------------- launch ----------------
extern "C" void kernel_launch(void* const* d_in, const int* in_sizes, int n_in,
                              void* d_out, int out_size, void* d_ws, size_t ws_size,
                              hipStream_t stream) {
    const float* x  = (const float*)d_in[0];
    const int*   ei = (const int*)d_in[1];
    const float* ew = (const float*)d_in[2];
    const float* W1 = (const float*)d_in[3];
    const float* b1 = (const float*)d_in[4];
    const float* W2 = (const float*)d_in[5];
    const float* b2 = (const float*)d_in[6];
    float* out = (float*)d_out;

    char* ws = (char*)d_ws;
    // ws layout (bytes), total ~57.4 MB:
    uint2*          raw      = (uint2*)         (ws + 0);           // PBLK*EPB uint2 = 25,690,112
    int*            offs     = (int*)           (ws + 25690112);    // PBLK*NBP1 int = 1,227,744 -> 26,917,856, pad
    int*            offsT    = (int*)           (ws + 26917888);    // NBP1*PBLK int -> 28,145,632, pad
    unsigned*       srt1     = (unsigned*)      (ws + 28145664);    // NB*SSPAN u32 = 14,413,824 -> 42,559,488
    unsigned short* srt2     = (unsigned short*)(ws + 42559488);    // NB*SSPAN u16 = 7,206,912 -> 49,766,400
    int*            rowstart = (int*)           (ws + 49766400);    // NN ints -> 50,166,400
    int*            rowcnt   = (int*)           (ws + 50166400);    // NN ints -> 50,566,400
    float*          dinv     = (float*)         (ws + 50566400);    // NN floats -> 50,966,400
    bf16*           hs       = (bf16*)          (ws + 50966400);    // NN*HID bf16 -> 57,366,400
    unsigned short* wfrag    = (unsigned short*)(ws + 57366400);    // 8 KB -> 57,374,592

    k_w1frag<<<1, 64, 0, stream>>>(W1, wfrag);
    k_part<<<PBLK, 512, 0, stream>>>(ei, ew, offs, raw);
    k_trans<<<dim3((NBP1 + 31) / 32, (PBLK + 31) / 32), 256, 0, stream>>>(offs, offsT);
    k_sort<<<NB, 256, 0, stream>>>(offsT, raw, srt1, srt2, rowstart, rowcnt, dinv);
    k_hs<<<(NN + 63) / 64, 256, 0, stream>>>(x, wfrag, dinv, hs);
    k_agg<<<NN / 16, 256, 0, stream>>>(rowstart, rowcnt, srt1, srt2, hs, dinv, b1, W2, b2, out);
}

// Round 10
// 227.372 us; speedup vs baseline: 1.2829x; 1.2829x over previous
//
#include <hip/hip_runtime.h>
#include <hip/hip_bf16.h>
#include <hip/hip_fp16.h>

#define NN 100000
#define NE 3200000
#define IN_F 128
#define HID 32

#define NB 782          // buckets: bucket = dst >> 7, 128 nodes each
#define NBP1 (NB + 1)
#define BNODES 128
#define PBLK 782        // partition blocks
#define EPB 4096        // edges per partition block (512 thr x 8)
#define SSPAN 4608      // sorted span per bucket (mean 4092 + 8 sigma)

typedef __hip_bfloat16 bf16;
typedef __attribute__((ext_vector_type(8))) short s16x8;   // 8 bf16 (4 VGPRs)
typedef __attribute__((ext_vector_type(4))) float f32x4;   // MFMA C/D

// ---------------- partition: LDS counting sort, ALL global writes dense ----------------
__global__ __launch_bounds__(512) void k_part(const int* __restrict__ ei,
                                              const float* __restrict__ ew,
                                              int* __restrict__ offs,
                                              uint2* __restrict__ raw) {
    __shared__ int hist[NB];
    __shared__ int start[NB];
    __shared__ int wtot8[8];
    __shared__ uint2 sp[EPB];             // 32 KB

    int t = threadIdx.x;
    int blk = blockIdx.x;
    for (int b = t; b < NB; b += 512) hist[b] = 0;
    __syncthreads();

    unsigned pk[8]; unsigned wb[8]; int bkt[8];
    int base_e = blk * EPB;
#pragma unroll
    for (int j = 0; j < 8; j++) {
        int e = base_e + j * 512 + t;
        if (e < NE) {
            int src = __builtin_nontemporal_load(ei + e);
            int dst = __builtin_nontemporal_load(ei + NE + e);
            float w = __builtin_nontemporal_load(ew + e);
            bkt[j] = dst >> 7;
            pk[j] = (unsigned)src | ((unsigned)(dst & 127) << 20);
            wb[j] = __float_as_uint(w);
        } else bkt[j] = -1;
    }
#pragma unroll
    for (int j = 0; j < 8; j++)
        if (bkt[j] >= 0) atomicAdd(&hist[bkt[j]], 1);
    __syncthreads();

    // exclusive scan over 782 bins (512 threads x 2, shuffle-based)
    int e0 = 2 * t, e1 = 2 * t + 1;
    int h0 = (e0 < NB) ? hist[e0] : 0;
    int h1 = (e1 < NB) ? hist[e1] : 0;
    int psum = h0 + h1;
    int lane = t & 63;
    int incl = psum;
#pragma unroll
    for (int off = 1; off < 64; off <<= 1) {
        int up = __shfl_up(incl, off, 64);
        if (lane >= off) incl += up;
    }
    int wid = t >> 6;
    if (lane == 63) wtot8[wid] = incl;
    __syncthreads();
    int woff = 0;
    for (int wj = 0; wj < wid; wj++) woff += wtot8[wj];
    int exc = woff + incl - psum;
    if (e0 < NB) start[e0] = exc;
    if (e1 < NB) start[e1] = exc + h0;
    __syncthreads();

    int total = start[NB - 1] + hist[NB - 1];
    int* orow = offs + (size_t)blk * NBP1;
    for (int b = t; b < NB; b += 512) orow[b] = start[b];
    if (t == 0) orow[NB] = total;
    __syncthreads();   // orow reads of start[] complete before cursor mutation

    // LDS counting scatter (start[] becomes cursor)
#pragma unroll
    for (int j = 0; j < 8; j++) {
        if (bkt[j] >= 0) {
            int pos = atomicAdd(&start[bkt[j]], 1);
            sp[pos] = make_uint2(pk[j], wb[j]);
        }
    }
    __syncthreads();

    // dense, coalesced copy to block-private region (written exactly once)
    uint2* r = raw + (size_t)blk * EPB;
    for (int i = t; i < total; i += 512) r[i] = sp[i];
}

// ---------------- offs transpose ([blk][bucket] -> [bucket][blk]) ----------------
__global__ __launch_bounds__(256) void k_trans(const int* __restrict__ in, int* __restrict__ out) {
    __shared__ int tile[32][33];
    int c0 = blockIdx.x * 32, r0 = blockIdx.y * 32;
    int tx = threadIdx.x & 31, ty = threadIdx.x >> 5;   // 32 x 8
    for (int i = ty; i < 32; i += 8) {
        int r = r0 + i, c = c0 + tx;
        if (r < PBLK && c < NBP1) tile[i][tx] = in[(size_t)r * NBP1 + c];
    }
    __syncthreads();
    for (int i = ty; i < 32; i += 8) {
        int c = c0 + i, r = r0 + tx;
        if (c < NBP1 && r < PBLK) out[(size_t)c * PBLK + r] = tile[tx][i];
    }
}

// ---------------- per-bucket parallel gather + counting sort + CSR meta ----------------
__global__ __launch_bounds__(256) void k_sort(const int* __restrict__ offsT,
                                              const uint2* __restrict__ raw,
                                              uint2* __restrict__ srt,
                                              int* __restrict__ rowstart,
                                              int* __restrict__ rowcnt,
                                              float* __restrict__ dinv) {
    __shared__ uint2 se[SSPAN];               // 36.9 KB
    __shared__ unsigned short runid[SSPAN];   //  9.2 KB
    __shared__ int P[PBLK + 1];
    __shared__ int O0[PBLK];
    __shared__ int hist[BNODES];
    __shared__ float wsum[BNODES];
    __shared__ int scanbuf[BNODES];
    __shared__ int cur[BNODES];
    __shared__ int wt4[4];

    int t = threadIdx.x;
    int b = blockIdx.x;
    if (t < BNODES) { hist[t] = 0; wsum[t] = 1.0f; }  // self-loop weight 1

    // run lengths for this bucket across 782 partition blocks: 4 per thread
    int i0 = 4 * t;
    int L[4], O[4];
#pragma unroll
    for (int k = 0; k < 4; k++) {
        int idx = i0 + k;
        if (idx < PBLK) {
            int o = offsT[(size_t)b * PBLK + idx];
            O[k] = o;
            L[k] = offsT[(size_t)(b + 1) * PBLK + idx] - o;
        } else { O[k] = 0; L[k] = 0; }
    }
    int psum = L[0] + L[1] + L[2] + L[3];
    int lane = t & 63;
    int incl = psum;
#pragma unroll
    for (int off = 1; off < 64; off <<= 1) {
        int up = __shfl_up(incl, off, 64);
        if (lane >= off) incl += up;
    }
    int wid = t >> 6;
    if (lane == 63) wt4[wid] = incl;
    __syncthreads();
    int woff = 0;
    for (int wj = 0; wj < wid; wj++) woff += wt4[wj];
    int run = woff + incl - psum;
#pragma unroll
    for (int k = 0; k < 4; k++) {
        int idx = i0 + k;
        if (idx < PBLK) { P[idx] = run; O0[idx] = O[k]; run += L[k]; }
    }
    if (t == 0) P[PBLK] = wt4[0] + wt4[1] + wt4[2] + wt4[3];
    __syncthreads();

    int total = min(P[PBLK], SSPAN);

    // build d -> run map (short serial LDS fills, ~5 per run)
    for (int r = t; r < PBLK; r += 256) {
        int p0 = P[r], p1 = min(P[r + 1], SSPAN);
        for (int i = p0; i < p1; i++) runid[i] = (unsigned short)r;
    }
    __syncthreads();

    // parallel coalesced gather (4-way MLP) + node histogram
    for (int d0 = 0; d0 < total; d0 += 1024) {
        uint2 rec[4]; int dd[4]; int nv = 0;
#pragma unroll
        for (int k = 0; k < 4; k++) {
            dd[k] = d0 + k * 256 + t;
            if (dd[k] < total) {
                int r = runid[dd[k]];
                rec[k] = raw[(size_t)r * EPB + O0[r] + (dd[k] - P[r])];
                nv = k + 1;
            }
        }
#pragma unroll
        for (int k = 0; k < 4; k++) {
            if (k < nv) {
                se[dd[k]] = rec[k];
                int dl = (rec[k].x >> 20) & 127;
                atomicAdd(&hist[dl], 1);
                atomicAdd(&wsum[dl], __uint_as_float(rec[k].y));
            }
        }
    }
    __syncthreads();

    // inclusive scan of node hist (Hillis-Steele over 128)
    if (t < BNODES) scanbuf[t] = hist[t];
    __syncthreads();
    for (int off = 1; off < BNODES; off <<= 1) {
        int v = 0;
        if (t < BNODES && t >= off) v = scanbuf[t - off];
        __syncthreads();
        if (t < BNODES) scanbuf[t] += v;
        __syncthreads();
    }

    int obase = b * SSPAN;
    if (t < BNODES) {
        int binstart = scanbuf[t] - hist[t];  // exclusive
        cur[t] = binstart;
        int node = b * BNODES + t;
        if (node < NN) {
            rowstart[node] = obase + binstart;
            rowcnt[node]   = hist[t];
            dinv[node]     = rsqrtf(wsum[t]);
        }
    }
    __syncthreads();

    // scatter sorted by node (dense within bucket span)
    for (int i = t; i < total; i += 256) {
        uint2 rec = se[i];
        int dl = (rec.x >> 20) & 127;
        int pos = atomicAdd(&cur[dl], 1);     // LDS atomic
        srt[obase + pos] = make_uint2(rec.x & 0xFFFFF, rec.y);
    }
}

// ---------------- W1 -> bf16 MFMA B-fragments, lane-packed ----------------
__global__ void k_w1frag(const float* __restrict__ W1, unsigned short* __restrict__ wfrag) {
    int lane = threadIdx.x;   // 64 threads
    int q = lane >> 4;
    int n0 = lane & 15;
#pragma unroll
    for (int ks = 0; ks < 4; ks++) {
#pragma unroll
        for (int nt = 0; nt < 2; nt++) {
            int fi = ks * 2 + nt;
            int n = n0 + 16 * nt;
#pragma unroll
            for (int j = 0; j < 8; j++) {
                int k = ks * 32 + q * 8 + j;
                float v = W1[k * HID + n];
                __hip_bfloat16 bv = __float2bfloat16(v);
                wfrag[((size_t)fi * 64 + lane) * 8 + j] = *(unsigned short*)&bv;
            }
        }
    }
}

// ---------------- hs = dinv * (x @ W1) via MFMA, stored bf16 ----------------
__global__ __launch_bounds__(256) void k_hs(const float* __restrict__ x,
                                            const unsigned short* __restrict__ wfrag,
                                            const float* __restrict__ dinv,
                                            bf16* __restrict__ hs) {
    int t = threadIdx.x;
    int lane = t & 63;
    int wv = t >> 6;
    int base = blockIdx.x * 64 + wv * 16;
    int m = lane & 15;
    int q = lane >> 4;
    int node = base + m;

    s16x8 wf[8];
    const s16x8* wp = (const s16x8*)wfrag;
#pragma unroll
    for (int fi = 0; fi < 8; fi++) wf[fi] = wp[fi * 64 + lane];

    f32x4 acc0 = {0.f, 0.f, 0.f, 0.f};
    f32x4 acc1 = {0.f, 0.f, 0.f, 0.f};

    const float* rowp = x + (size_t)node * IN_F + q * 8;
    bool valid = (node < NN);

#pragma unroll
    for (int ks = 0; ks < 4; ks++) {
        float4 f0 = {0,0,0,0}, f1 = {0,0,0,0};
        if (valid) {
            const float4* xr = (const float4*)(rowp + ks * 32);
            f0 = xr[0]; f1 = xr[1];
        }
        union { s16x8 v; unsigned u32[4]; } af;
        __hip_bfloat162 p0 = __float22bfloat162_rn({f0.x, f0.y});
        __hip_bfloat162 p1 = __float22bfloat162_rn({f0.z, f0.w});
        __hip_bfloat162 p2 = __float22bfloat162_rn({f1.x, f1.y});
        __hip_bfloat162 p3 = __float22bfloat162_rn({f1.z, f1.w});
        af.u32[0] = *(unsigned*)&p0;
        af.u32[1] = *(unsigned*)&p1;
        af.u32[2] = *(unsigned*)&p2;
        af.u32[3] = *(unsigned*)&p3;
        acc0 = __builtin_amdgcn_mfma_f32_16x16x32_bf16(af.v, wf[ks * 2 + 0], acc0, 0, 0, 0);
        acc1 = __builtin_amdgcn_mfma_f32_16x16x32_bf16(af.v, wf[ks * 2 + 1], acc1, 0, 0, 0);
    }

    int f = lane & 15;
#pragma unroll
    for (int r = 0; r < 4; r++) {
        int n2 = base + q * 4 + r;
        if (n2 < NN) {
            float dv = dinv[n2];
            hs[(size_t)n2 * HID + f]      = __float2bfloat16(dv * acc0[r]);
            hs[(size_t)n2 * HID + f + 16] = __float2bfloat16(dv * acc1[r]);
        }
    }
}

// ---------------- node-parallel pull aggregation + fused epilogue ----------------
// 16 lanes/node x 2 feats/lane (wave = 4 nodes); 8B uint2 record per edge.
__global__ __launch_bounds__(256) void k_agg(const int* __restrict__ rowstart,
                                             const int* __restrict__ rowcnt,
                                             const uint2* __restrict__ eb,
                                             const bf16* __restrict__ hs,
                                             const float* __restrict__ dinv,
                                             const float* __restrict__ b1, const float* __restrict__ W2,
                                             const float* __restrict__ b2, float* __restrict__ out) {
    int t = threadIdx.x;
    int l = t & 15;                          // lane within node group
    int node = blockIdx.x * 16 + (t >> 4);   // NN % 16 == 0
    int rs = rowstart[node];
    int re = rs + rowcnt[node];
    const __hip_bfloat162* hs2 = (const __hip_bfloat162*)hs;  // row stride 16
    float acc0 = 0.f, acc1 = 0.f;

    for (int base = rs; base < re; base += 16) {
        int idx = base + l;
        int sreg = 0; float wreg = 0.f;
        if (idx < re) {
            uint2 r = eb[idx];
            sreg = (int)r.x;
            wreg = __uint_as_float(r.y);
        }
        int m = min(16, re - base);
        int j = 0;
        for (; j + 8 <= m; j += 8) {
            int s0 = __shfl(sreg, j + 0, 16), s1 = __shfl(sreg, j + 1, 16);
            int s2 = __shfl(sreg, j + 2, 16), s3 = __shfl(sreg, j + 3, 16);
            int s4 = __shfl(sreg, j + 4, 16), s5 = __shfl(sreg, j + 5, 16);
            int s6 = __shfl(sreg, j + 6, 16), s7 = __shfl(sreg, j + 7, 16);
            float w0 = __shfl(wreg, j + 0, 16), w1 = __shfl(wreg, j + 1, 16);
            float w2 = __shfl(wreg, j + 2, 16), w3 = __shfl(wreg, j + 3, 16);
            float w4 = __shfl(wreg, j + 4, 16), w5 = __shfl(wreg, j + 5, 16);
            float w6 = __shfl(wreg, j + 6, 16), w7 = __shfl(wreg, j + 7, 16);
            __hip_bfloat162 h0 = hs2[(size_t)s0 * 16 + l];
            __hip_bfloat162 h1 = hs2[(size_t)s1 * 16 + l];
            __hip_bfloat162 h2 = hs2[(size_t)s2 * 16 + l];
            __hip_bfloat162 h3 = hs2[(size_t)s3 * 16 + l];
            __hip_bfloat162 h4 = hs2[(size_t)s4 * 16 + l];
            __hip_bfloat162 h5 = hs2[(size_t)s5 * 16 + l];
            __hip_bfloat162 h6 = hs2[(size_t)s6 * 16 + l];
            __hip_bfloat162 h7 = hs2[(size_t)s7 * 16 + l];
            float2 f0 = __bfloat1622float2(h0); acc0 += w0 * f0.x; acc1 += w0 * f0.y;
            float2 f1 = __bfloat1622float2(h1); acc0 += w1 * f1.x; acc1 += w1 * f1.y;
            float2 f2 = __bfloat1622float2(h2); acc0 += w2 * f2.x; acc1 += w2 * f2.y;
            float2 f3 = __bfloat1622float2(h3); acc0 += w3 * f3.x; acc1 += w3 * f3.y;
            float2 f4 = __bfloat1622float2(h4); acc0 += w4 * f4.x; acc1 += w4 * f4.y;
            float2 f5 = __bfloat1622float2(h5); acc0 += w5 * f5.x; acc1 += w5 * f5.y;
            float2 f6 = __bfloat1622float2(h6); acc0 += w6 * f6.x; acc1 += w6 * f6.y;
            float2 f7 = __bfloat1622float2(h7); acc0 += w7 * f7.x; acc1 += w7 * f7.y;
        }
        for (; j < m; j++) {
            int s = __shfl(sreg, j, 16);
            float w = __shfl(wreg, j, 16);
            float2 fv = __bfloat1622float2(hs2[(size_t)s * 16 + l]);
            acc0 += w * fv.x; acc1 += w * fv.y;
        }
    }

    float2 fs = __bfloat1622float2(hs2[(size_t)node * 16 + l]);
    float dv = dinv[node];
    float v0 = dv * (acc0 + fs.x) + b1[2 * l];
    float v1 = dv * (acc1 + fs.y) + b1[2 * l + 1];
    v0 = fmaxf(v0, 0.f);
    v1 = fmaxf(v1, 0.f);
    float psum = v0 * W2[2 * l] + v1 * W2[2 * l + 1];
#pragma unroll
    for (int m2 = 8; m2 >= 1; m2 >>= 1) psum += __shfl_xor(psum, m2, 16);
    if (l == 0) out[node] = psum + b2[0];
}

// ---------------- launch ----------------
extern "C" void kernel_launch(void* const* d_in, const int* in_sizes, int n_in,
                              void* d_out, int out_size, void* d_ws, size_t ws_size,
                              hipStream_t stream) {
    const float* x  = (const float*)d_in[0];
    const int*   ei = (const int*)d_in[1];
    const float* ew = (const float*)d_in[2];
    const float* W1 = (const float*)d_in[3];
    const float* b1 = (const float*)d_in[4];
    const float* W2 = (const float*)d_in[5];
    const float* b2 = (const float*)d_in[6];
    float* out = (float*)d_out;

    char* ws = (char*)d_ws;
    // ws layout (bytes), total ~60.6 MB. hs OVERLAPS raw (raw dead after k_sort;
    // stream-ordered k_part -> k_sort -> k_hs -> k_agg makes this safe).
    uint2*          raw      = (uint2*)         (ws + 0);           // PBLK*EPB uint2 = 25,624,576
    bf16*           hs       = (bf16*)          (ws + 0);           // NN*HID bf16 = 6,400,000 (overlaps raw)
    int*            offs     = (int*)           (ws + 25624576);    // PBLK*NBP1 int = 2,449,224 -> 28,073,800 pad
    int*            offsT    = (int*)           (ws + 28073984);    // NBP1*PBLK int -> 30,523,208 pad
    uint2*          srt      = (uint2*)         (ws + 30523392);    // NB*SSPAN uint2 = 28,827,648 -> 59,351,040
    int*            rowstart = (int*)           (ws + 59351040);    // NN ints -> 59,751,040
    int*            rowcnt   = (int*)           (ws + 59751040);    // NN ints -> 60,151,040
    float*          dinv     = (float*)         (ws + 60151040);    // NN floats -> 60,551,040
    unsigned short* wfrag    = (unsigned short*)(ws + 60551040);    // 8 KB -> 60,559,232

    k_w1frag<<<1, 64, 0, stream>>>(W1, wfrag);
    k_part<<<PBLK, 512, 0, stream>>>(ei, ew, offs, raw);
    k_trans<<<dim3((NBP1 + 31) / 32, (PBLK + 31) / 32), 256, 0, stream>>>(offs, offsT);
    k_sort<<<NB, 256, 0, stream>>>(offsT, raw, srt, rowstart, rowcnt, dinv);
    k_hs<<<(NN + 63) / 64, 256, 0, stream>>>(x, wfrag, dinv, hs);
    k_agg<<<NN / 16, 256, 0, stream>>>(rowstart, rowcnt, srt, hs, dinv, b1, W2, b2, out);
}

// Round 11
// 215.109 us; speedup vs baseline: 1.3560x; 1.0570x over previous
//
#include <hip/hip_runtime.h>
#include <hip/hip_bf16.h>
#include <hip/hip_fp16.h>

#define NN 100000
#define NE 3200000
#define IN_F 128
#define HID 32

#define NB 782          // buckets: bucket = dst >> 7, 128 nodes each
#define NBP1 (NB + 1)
#define BNODES 128
#define PBLK 782        // partition blocks
#define EPB 4096        // edges per partition block (512 thr x 8)
#define SSPAN 4608      // sorted span per bucket (mean 4092 + 8 sigma); = 9*512

typedef __hip_bfloat16 bf16;
typedef __attribute__((ext_vector_type(8))) short s16x8;   // 8 bf16 (4 VGPRs)
typedef __attribute__((ext_vector_type(4))) float f32x4;   // MFMA C/D

// ---------------- partition: LDS counting sort, ALL global writes dense ----------------
__global__ __launch_bounds__(512) void k_part(const int* __restrict__ ei,
                                              const float* __restrict__ ew,
                                              int* __restrict__ offs,
                                              uint2* __restrict__ raw) {
    __shared__ int hist[NB];
    __shared__ int start[NB];
    __shared__ int wtot8[8];
    __shared__ uint2 sp[EPB];             // 32 KB

    int t = threadIdx.x;
    int blk = blockIdx.x;
    for (int b = t; b < NB; b += 512) hist[b] = 0;
    __syncthreads();

    unsigned pk[8]; unsigned wb[8]; int bkt[8];
    int base_e = blk * EPB;
#pragma unroll
    for (int j = 0; j < 8; j++) {
        int e = base_e + j * 512 + t;
        if (e < NE) {
            int src = __builtin_nontemporal_load(ei + e);
            int dst = __builtin_nontemporal_load(ei + NE + e);
            float w = __builtin_nontemporal_load(ew + e);
            bkt[j] = dst >> 7;
            pk[j] = (unsigned)src | ((unsigned)(dst & 127) << 20);
            wb[j] = __float_as_uint(w);
        } else bkt[j] = -1;
    }
#pragma unroll
    for (int j = 0; j < 8; j++)
        if (bkt[j] >= 0) atomicAdd(&hist[bkt[j]], 1);
    __syncthreads();

    // exclusive scan over 782 bins (512 threads x 2, shuffle-based)
    int e0 = 2 * t, e1 = 2 * t + 1;
    int h0 = (e0 < NB) ? hist[e0] : 0;
    int h1 = (e1 < NB) ? hist[e1] : 0;
    int psum = h0 + h1;
    int lane = t & 63;
    int incl = psum;
#pragma unroll
    for (int off = 1; off < 64; off <<= 1) {
        int up = __shfl_up(incl, off, 64);
        if (lane >= off) incl += up;
    }
    int wid = t >> 6;
    if (lane == 63) wtot8[wid] = incl;
    __syncthreads();
    int woff = 0;
    for (int wj = 0; wj < wid; wj++) woff += wtot8[wj];
    int exc = woff + incl - psum;
    if (e0 < NB) start[e0] = exc;
    if (e1 < NB) start[e1] = exc + h0;
    __syncthreads();

    int total = start[NB - 1] + hist[NB - 1];
    int* orow = offs + (size_t)blk * NBP1;
    for (int b = t; b < NB; b += 512) orow[b] = start[b];
    if (t == 0) orow[NB] = total;
    __syncthreads();   // orow reads of start[] complete before cursor mutation

    // LDS counting scatter (start[] becomes cursor)
#pragma unroll
    for (int j = 0; j < 8; j++) {
        if (bkt[j] >= 0) {
            int pos = atomicAdd(&start[bkt[j]], 1);
            sp[pos] = make_uint2(pk[j], wb[j]);
        }
    }
    __syncthreads();

    // dense, coalesced copy to block-private region (written exactly once)
    uint2* r = raw + (size_t)blk * EPB;
    for (int i = t; i < total; i += 512) r[i] = sp[i];
}

// ---------------- offs transpose ([blk][bucket] -> [bucket][blk]) ----------------
__global__ __launch_bounds__(256) void k_trans(const int* __restrict__ in, int* __restrict__ out) {
    __shared__ int tile[32][33];
    int c0 = blockIdx.x * 32, r0 = blockIdx.y * 32;
    int tx = threadIdx.x & 31, ty = threadIdx.x >> 5;   // 32 x 8
    for (int i = ty; i < 32; i += 8) {
        int r = r0 + i, c = c0 + tx;
        if (r < PBLK && c < NBP1) tile[i][tx] = in[(size_t)r * NBP1 + c];
    }
    __syncthreads();
    for (int i = ty; i < 32; i += 8) {
        int c = c0 + i, r = r0 + tx;
        if (c < NBP1 && r < PBLK) out[(size_t)c * PBLK + r] = tile[tx][i];
    }
}

// ---------------- per-bucket gather + counting sort (register-staged, dense out) ----------------
__global__ __launch_bounds__(512) void k_sort(const int* __restrict__ offsT,
                                              const uint2* __restrict__ raw,
                                              uint2* __restrict__ srt,
                                              int* __restrict__ rowstart,
                                              int* __restrict__ rowcnt,
                                              float* __restrict__ dinv) {
    __shared__ uint2 se[SSPAN];               // 36.9 KB (sorted records)
    __shared__ unsigned short runid[SSPAN];   //  9.2 KB
    __shared__ int P[PBLK + 1];
    __shared__ int O0[PBLK];
    __shared__ int hist[BNODES];
    __shared__ float wsum[BNODES];
    __shared__ int scanbuf[BNODES];
    __shared__ int cur[BNODES];
    __shared__ int wt8[8];

    int t = threadIdx.x;
    int b = blockIdx.x;
    if (t < BNODES) { hist[t] = 0; wsum[t] = 1.0f; }  // self-loop weight 1

    // run lengths for this bucket across 782 partition blocks (2 per thread)
    int e0 = 2 * t, e1 = 2 * t + 1;
    int l0 = 0, l1 = 0, o0v = 0, o1v = 0;
    if (e0 < PBLK) {
        o0v = offsT[(size_t)b * PBLK + e0];
        l0  = offsT[(size_t)(b + 1) * PBLK + e0] - o0v;
    }
    if (e1 < PBLK) {
        o1v = offsT[(size_t)b * PBLK + e1];
        l1  = offsT[(size_t)(b + 1) * PBLK + e1] - o1v;
    }
    int psum = l0 + l1;
    int lane = t & 63;
    int incl = psum;
#pragma unroll
    for (int off = 1; off < 64; off <<= 1) {
        int up = __shfl_up(incl, off, 64);
        if (lane >= off) incl += up;
    }
    int wid = t >> 6;
    if (lane == 63) wt8[wid] = incl;
    __syncthreads();
    int woff = 0;
    for (int wj = 0; wj < wid; wj++) woff += wt8[wj];
    int exc = woff + incl - psum;
    if (e0 < PBLK) { P[e0] = exc;      O0[e0] = o0v; }
    if (e1 < PBLK) { P[e1] = exc + l0; O0[e1] = o1v; }
    if (t == 0) {
        int s = 0;
#pragma unroll
        for (int j = 0; j < 8; j++) s += wt8[j];
        P[PBLK] = s;
    }
    __syncthreads();

    int total = min(P[PBLK], SSPAN);

    // build d -> run map (short serial LDS fills, ~5 per run)
    for (int r = t; r < PBLK; r += 512) {
        int p0 = P[r], p1 = min(P[r + 1], SSPAN);
        for (int i = p0; i < p1; i++) runid[i] = (unsigned short)r;
    }
    __syncthreads();

    // pass 1: coalesced gather into REGISTERS + node histogram (<=9 recs/thread)
    uint2 rr[9];
#pragma unroll
    for (int k = 0; k < 9; k++) {
        int d = t + k * 512;
        if (d < total) {
            int r = runid[d];
            uint2 rec = raw[(size_t)r * EPB + O0[r] + (d - P[r])];
            rr[k] = rec;
            int dl = (rec.x >> 20) & 127;
            atomicAdd(&hist[dl], 1);
            atomicAdd(&wsum[dl], __uint_as_float(rec.y));
        }
    }
    __syncthreads();

    // inclusive scan of node hist (Hillis-Steele over 128)
    if (t < BNODES) scanbuf[t] = hist[t];
    __syncthreads();
    for (int off = 1; off < BNODES; off <<= 1) {
        int v = 0;
        if (t < BNODES && t >= off) v = scanbuf[t - off];
        __syncthreads();
        if (t < BNODES) scanbuf[t] += v;
        __syncthreads();
    }

    int obase = b * SSPAN;
    if (t < BNODES) {
        int binstart = scanbuf[t] - hist[t];  // exclusive
        cur[t] = binstart;
        int node = b * BNODES + t;
        if (node < NN) {
            rowstart[node] = obase + binstart;
            rowcnt[node]   = hist[t];
            dinv[node]     = rsqrtf(wsum[t]);
        }
    }
    __syncthreads();

    // pass 2: scatter from registers into se at final sorted positions
#pragma unroll
    for (int k = 0; k < 9; k++) {
        int d = t + k * 512;
        if (d < total) {
            uint2 rec = rr[k];
            int dl = (rec.x >> 20) & 127;
            int pos = atomicAdd(&cur[dl], 1);   // LDS atomic
            se[pos] = make_uint2(rec.x & 0xFFFFF, rec.y);
        }
    }
    __syncthreads();

    // dense, fully-coalesced store-out (no partial lines, no RFO)
    for (int i = t; i < total; i += 512) srt[obase + i] = se[i];
}

// ---------------- W1 -> bf16 MFMA B-fragments, lane-packed ----------------
__global__ void k_w1frag(const float* __restrict__ W1, unsigned short* __restrict__ wfrag) {
    int lane = threadIdx.x;   // 64 threads
    int q = lane >> 4;
    int n0 = lane & 15;
#pragma unroll
    for (int ks = 0; ks < 4; ks++) {
#pragma unroll
        for (int nt = 0; nt < 2; nt++) {
            int fi = ks * 2 + nt;
            int n = n0 + 16 * nt;
#pragma unroll
            for (int j = 0; j < 8; j++) {
                int k = ks * 32 + q * 8 + j;
                float v = W1[k * HID + n];
                __hip_bfloat16 bv = __float2bfloat16(v);
                wfrag[((size_t)fi * 64 + lane) * 8 + j] = *(unsigned short*)&bv;
            }
        }
    }
}

// ---------------- hs = dinv * (x @ W1) via MFMA, stored bf16 ----------------
__global__ __launch_bounds__(256) void k_hs(const float* __restrict__ x,
                                            const unsigned short* __restrict__ wfrag,
                                            const float* __restrict__ dinv,
                                            bf16* __restrict__ hs) {
    int t = threadIdx.x;
    int lane = t & 63;
    int wv = t >> 6;
    int base = blockIdx.x * 64 + wv * 16;
    int m = lane & 15;
    int q = lane >> 4;
    int node = base + m;

    s16x8 wf[8];
    const s16x8* wp = (const s16x8*)wfrag;
#pragma unroll
    for (int fi = 0; fi < 8; fi++) wf[fi] = wp[fi * 64 + lane];

    f32x4 acc0 = {0.f, 0.f, 0.f, 0.f};
    f32x4 acc1 = {0.f, 0.f, 0.f, 0.f};

    const float* rowp = x + (size_t)node * IN_F + q * 8;
    bool valid = (node < NN);

#pragma unroll
    for (int ks = 0; ks < 4; ks++) {
        float4 f0 = {0,0,0,0}, f1 = {0,0,0,0};
        if (valid) {
            const float4* xr = (const float4*)(rowp + ks * 32);
            f0 = xr[0]; f1 = xr[1];
        }
        union { s16x8 v; unsigned u32[4]; } af;
        __hip_bfloat162 p0 = __float22bfloat162_rn({f0.x, f0.y});
        __hip_bfloat162 p1 = __float22bfloat162_rn({f0.z, f0.w});
        __hip_bfloat162 p2 = __float22bfloat162_rn({f1.x, f1.y});
        __hip_bfloat162 p3 = __float22bfloat162_rn({f1.z, f1.w});
        af.u32[0] = *(unsigned*)&p0;
        af.u32[1] = *(unsigned*)&p1;
        af.u32[2] = *(unsigned*)&p2;
        af.u32[3] = *(unsigned*)&p3;
        acc0 = __builtin_amdgcn_mfma_f32_16x16x32_bf16(af.v, wf[ks * 2 + 0], acc0, 0, 0, 0);
        acc1 = __builtin_amdgcn_mfma_f32_16x16x32_bf16(af.v, wf[ks * 2 + 1], acc1, 0, 0, 0);
    }

    int f = lane & 15;
#pragma unroll
    for (int r = 0; r < 4; r++) {
        int n2 = base + q * 4 + r;
        if (n2 < NN) {
            float dv = dinv[n2];
            hs[(size_t)n2 * HID + f]      = __float2bfloat16(dv * acc0[r]);
            hs[(size_t)n2 * HID + f + 16] = __float2bfloat16(dv * acc1[r]);
        }
    }
}

// ---------------- node-parallel pull aggregation + fused epilogue ----------------
// 16 lanes/node x 2 feats/lane (wave = 4 nodes); 8B uint2 record per edge.
__global__ __launch_bounds__(256) void k_agg(const int* __restrict__ rowstart,
                                             const int* __restrict__ rowcnt,
                                             const uint2* __restrict__ eb,
                                             const bf16* __restrict__ hs,
                                             const float* __restrict__ dinv,
                                             const float* __restrict__ b1, const float* __restrict__ W2,
                                             const float* __restrict__ b2, float* __restrict__ out) {
    int t = threadIdx.x;
    int l = t & 15;                          // lane within node group
    int node = blockIdx.x * 16 + (t >> 4);   // NN % 16 == 0
    int rs = rowstart[node];
    int re = rs + rowcnt[node];
    const __hip_bfloat162* hs2 = (const __hip_bfloat162*)hs;  // row stride 16
    float acc0 = 0.f, acc1 = 0.f;

    for (int base = rs; base < re; base += 16) {
        int idx = base + l;
        int sreg = 0; float wreg = 0.f;
        if (idx < re) {
            uint2 r = eb[idx];
            sreg = (int)r.x;
            wreg = __uint_as_float(r.y);
        }
        int m = min(16, re - base);
        int j = 0;
        for (; j + 8 <= m; j += 8) {
            int s0 = __shfl(sreg, j + 0, 16), s1 = __shfl(sreg, j + 1, 16);
            int s2 = __shfl(sreg, j + 2, 16), s3 = __shfl(sreg, j + 3, 16);
            int s4 = __shfl(sreg, j + 4, 16), s5 = __shfl(sreg, j + 5, 16);
            int s6 = __shfl(sreg, j + 6, 16), s7 = __shfl(sreg, j + 7, 16);
            float w0 = __shfl(wreg, j + 0, 16), w1 = __shfl(wreg, j + 1, 16);
            float w2 = __shfl(wreg, j + 2, 16), w3 = __shfl(wreg, j + 3, 16);
            float w4 = __shfl(wreg, j + 4, 16), w5 = __shfl(wreg, j + 5, 16);
            float w6 = __shfl(wreg, j + 6, 16), w7 = __shfl(wreg, j + 7, 16);
            __hip_bfloat162 h0 = hs2[(size_t)s0 * 16 + l];
            __hip_bfloat162 h1 = hs2[(size_t)s1 * 16 + l];
            __hip_bfloat162 h2 = hs2[(size_t)s2 * 16 + l];
            __hip_bfloat162 h3 = hs2[(size_t)s3 * 16 + l];
            __hip_bfloat162 h4 = hs2[(size_t)s4 * 16 + l];
            __hip_bfloat162 h5 = hs2[(size_t)s5 * 16 + l];
            __hip_bfloat162 h6 = hs2[(size_t)s6 * 16 + l];
            __hip_bfloat162 h7 = hs2[(size_t)s7 * 16 + l];
            float2 f0 = __bfloat1622float2(h0); acc0 += w0 * f0.x; acc1 += w0 * f0.y;
            float2 f1 = __bfloat1622float2(h1); acc0 += w1 * f1.x; acc1 += w1 * f1.y;
            float2 f2 = __bfloat1622float2(h2); acc0 += w2 * f2.x; acc1 += w2 * f2.y;
            float2 f3 = __bfloat1622float2(h3); acc0 += w3 * f3.x; acc1 += w3 * f3.y;
            float2 f4 = __bfloat1622float2(h4); acc0 += w4 * f4.x; acc1 += w4 * f4.y;
            float2 f5 = __bfloat1622float2(h5); acc0 += w5 * f5.x; acc1 += w5 * f5.y;
            float2 f6 = __bfloat1622float2(h6); acc0 += w6 * f6.x; acc1 += w6 * f6.y;
            float2 f7 = __bfloat1622float2(h7); acc0 += w7 * f7.x; acc1 += w7 * f7.y;
        }
        for (; j < m; j++) {
            int s = __shfl(sreg, j, 16);
            float w = __shfl(wreg, j, 16);
            float2 fv = __bfloat1622float2(hs2[(size_t)s * 16 + l]);
            acc0 += w * fv.x; acc1 += w * fv.y;
        }
    }

    float2 fs = __bfloat1622float2(hs2[(size_t)node * 16 + l]);
    float dv = dinv[node];
    float v0 = dv * (acc0 + fs.x) + b1[2 * l];
    float v1 = dv * (acc1 + fs.y) + b1[2 * l + 1];
    v0 = fmaxf(v0, 0.f);
    v1 = fmaxf(v1, 0.f);
    float psum = v0 * W2[2 * l] + v1 * W2[2 * l + 1];
#pragma unroll
    for (int m2 = 8; m2 >= 1; m2 >>= 1) psum += __shfl_xor(psum, m2, 16);
    if (l == 0) out[node] = psum + b2[0];
}

// ---------------- launch ----------------
extern "C" void kernel_launch(void* const* d_in, const int* in_sizes, int n_in,
                              void* d_out, int out_size, void* d_ws, size_t ws_size,
                              hipStream_t stream) {
    const float* x  = (const float*)d_in[0];
    const int*   ei = (const int*)d_in[1];
    const float* ew = (const float*)d_in[2];
    const float* W1 = (const float*)d_in[3];
    const float* b1 = (const float*)d_in[4];
    const float* W2 = (const float*)d_in[5];
    const float* b2 = (const float*)d_in[6];
    float* out = (float*)d_out;

    char* ws = (char*)d_ws;
    // ws layout (bytes), total ~60.6 MB. hs OVERLAPS raw (raw dead after k_sort;
    // stream-ordered k_part -> k_sort -> k_hs -> k_agg makes this safe).
    uint2*          raw      = (uint2*)         (ws + 0);           // PBLK*EPB uint2 = 25,624,576
    bf16*           hs       = (bf16*)          (ws + 0);           // NN*HID bf16 = 6,400,000 (overlaps raw)
    int*            offs     = (int*)           (ws + 25624576);    // PBLK*NBP1 int = 2,449,224 -> 28,073,800 pad
    int*            offsT    = (int*)           (ws + 28073984);    // NBP1*PBLK int -> 30,523,208 pad
    uint2*          srt      = (uint2*)         (ws + 30523392);    // NB*SSPAN uint2 = 28,827,648 -> 59,351,040
    int*            rowstart = (int*)           (ws + 59351040);    // NN ints -> 59,751,040
    int*            rowcnt   = (int*)           (ws + 59751040);    // NN ints -> 60,151,040
    float*          dinv     = (float*)         (ws + 60151040);    // NN floats -> 60,551,040
    unsigned short* wfrag    = (unsigned short*)(ws + 60551040);    // 8 KB -> 60,559,232

    k_w1frag<<<1, 64, 0, stream>>>(W1, wfrag);
    k_part<<<PBLK, 512, 0, stream>>>(ei, ew, offs, raw);
    k_trans<<<dim3((NBP1 + 31) / 32, (PBLK + 31) / 32), 256, 0, stream>>>(offs, offsT);
    k_sort<<<NB, 512, 0, stream>>>(offsT, raw, srt, rowstart, rowcnt, dinv);
    k_hs<<<(NN + 63) / 64, 256, 0, stream>>>(x, wfrag, dinv, hs);
    k_agg<<<NN / 16, 256, 0, stream>>>(rowstart, rowcnt, srt, hs, dinv, b1, W2, b2, out);
}